// Round 1
// baseline (255.095 us; speedup 1.0000x reference)
//
#include <hip/hip_runtime.h>
#include <float.h>

#define NUM_EMB 512
#define DIM     128
#define HWX     4096          // 64*64 spatial per batch
#define NPOS    (32 * 4096)   // 131072 positions
#define MARGIN  0.35f         // fp16 noise (13+ sigma) + packed-score quantization (0.064)

// ---------------- workspace layout (bytes) ----------------
#define WS_E16   ((size_t)33554432)             // 512*128 fp16   = 131072
#define WS_ESQ   ((size_t)33685504)             // 512 fp32       = 2048
#define WS_WL    ((size_t)34211840)             // 131072 int     = 524288
#define WS_CNT   ((size_t)34736128)             // counter        = 256
#define WS_NEED  ((size_t)34736384)

using half8 = __attribute__((ext_vector_type(8))) _Float16;
using f32x4 = __attribute__((ext_vector_type(4))) float;

// ---------------- prep: e16[k][c], exact e_sq, zero counter ----------------
__global__ void prep_kernel(const float* __restrict__ emb, _Float16* __restrict__ e16,
                            float* __restrict__ esq, int* __restrict__ cnt) {
    int k = blockIdx.x * blockDim.x + threadIdx.x;
    if (k == 0) *cnt = 0;
    if (k < NUM_EMB) {
        const float4* row = (const float4*)(emb + (size_t)k * DIM);
        _Float16* dst = e16 + (size_t)k * DIM;
        float s0 = 0.f, s1 = 0.f, s2 = 0.f, s3 = 0.f;
        #pragma unroll
        for (int c = 0; c < DIM / 4; ++c) {
            float4 v = row[c];
            s0 = fmaf(v.x, v.x, s0);
            s1 = fmaf(v.y, v.y, s1);
            s2 = fmaf(v.z, v.z, s2);
            s3 = fmaf(v.w, v.w, s3);
            dst[4 * c + 0] = (_Float16)v.x;
            dst[4 * c + 1] = (_Float16)v.y;
            dst[4 * c + 2] = (_Float16)v.z;
            dst[4 * c + 3] = (_Float16)v.w;
        }
        esq[k] = (s0 + s1) + (s2 + s3);   // identical math to round-1 (verified exact vs numpy)
    }
}

// ---------------- gemm v5: vectorized prologue/epilogue over hw ----------------
// v4 was latency/issue-bound (all pipes <23%): 64 scalar dword loads (prologue)
// + 64 scalar dword stores (epilogue) per thread. v5: thread = 4 consecutive hw
// positions x 16 channels -> dwordx4 both directions (16 loads / 16+16 ld+st),
// 4x fewer latency rounds, same bytes. LDS A-tile: rows now step by 4 per lane,
// so slot is XOR-swizzled with (row>>2)&7; both the write pattern and the
// K-loop ds_read_b128 pattern sit exactly at the 8-access/bank b128 floor
// (verified arithmetically). Read-side swizzle folds to a lane-constant base
// (quad^(l15>>2)) + compile-time offsets (kc^(mt&1)) -- zero extra VALU.
// Everything else (streaming-B, packed top-2, butterfly, margin flag) as v4.
__global__ __launch_bounds__(256) void gemm_argmin(const float* __restrict__ z,
                                                   const _Float16* __restrict__ e16,
                                                   const float* __restrict__ esq,
                                                   const float* __restrict__ emb,
                                                   float* __restrict__ out,
                                                   int* __restrict__ wl,
                                                   int* __restrict__ cnt) {
    __shared__ __align__(16) char Ash[128 * 272];   // 128 pos rows, 272B stride
    __shared__ float mB1[2][128];
    __shared__ float mB2[2][128];
    __shared__ int   ish[128];

    int t = threadIdx.x;
    int lane = t & 63, wave = t >> 6;
    int wm = wave & 1, wn = wave >> 1;
    int quad = lane >> 4, l15 = lane & 15;
    int n0 = blockIdx.x * 128;
    int bb = n0 >> 12;
    int hw0 = n0 & 4095;          // block-aligned: same batch, contiguous 128 hw

    // ---- prologue: 4 consecutive positions x 16 channels per thread, dwordx4
    {
        int g = t & 31, cq = t >> 5;
        int hw = hw0 + 4 * g;
        const float* zp = z + (size_t)bb * DIM * HWX + (size_t)cq * 16 * HWX + hw;
        char* arow0 = Ash + (4 * g) * 272;
        int xr = g & 7;                         // = (row>>2)&7 for rows 4g..4g+3
        #pragma unroll
        for (int k = 0; k < 2; ++k) {           // two 8-channel chunks
            float4 v[8];
            #pragma unroll
            for (int c = 0; c < 8; ++c)
                v[c] = *(const float4*)(zp + (size_t)(k * 8 + c) * HWX);
            int slotb = ((2 * cq + k) ^ xr) * 16;   // swizzled 16B slot
            #pragma unroll
            for (int j = 0; j < 4; ++j) {       // register 4x4 transpose -> row j
                half8 hv;
                #pragma unroll
                for (int c = 0; c < 8; ++c) {
                    float f = (j == 0) ? v[c].x : (j == 1) ? v[c].y
                            : (j == 2) ? v[c].z : v[c].w;
                    hv[c] = (_Float16)f;
                }
                *(half8*)(arow0 + j * 272 + slotb) = hv;
            }
        }
    }
    __syncthreads();   // the ONLY barrier before the epilogue

    float b1[16], b2[16];
    #pragma unroll
    for (int s = 0; s < 16; ++s) { b1[s] = 3.0e38f; b2[s] = 3.0e38f; }

    // A-fragment base: row = wm*64 + mt*16 + l15; swizzle folds to lane-const
    const char* abase = Ash + (wm * 64 + l15) * 272 + (quad ^ (l15 >> 2)) * 16;
    const char* ebase = (const char*)e16 + ((size_t)(wn * 32 + l15) << 8) + quad * 16;
    const float* eqb  = esq + wn * 32 + l15;

    for (int tile = 0; tile < 8; ++tile) {
        // ---- B fragments: 8 dwordx4 from L2-hot e16, issued together
        half8 bf[2][4];
        {
            const char* eb = ebase + (size_t)tile * 64 * 256;
            #pragma unroll
            for (int nt = 0; nt < 2; ++nt)
                #pragma unroll
                for (int kc = 0; kc < 4; ++kc)
                    bf[nt][kc] = *(const half8*)(eb + nt * 4096 + kc * 64);
        }
        float es0 = eqb[tile * 64];
        float es1 = eqb[tile * 64 + 16];

        f32x4 acc[4][2];
        #pragma unroll
        for (int mt = 0; mt < 4; ++mt)
            #pragma unroll
            for (int nt = 0; nt < 2; ++nt)
                acc[mt][nt] = (f32x4){0.f, 0.f, 0.f, 0.f};

        #pragma unroll
        for (int kc = 0; kc < 4; ++kc) {
            half8 af[4];
            #pragma unroll
            for (int mt = 0; mt < 4; ++mt)
                af[mt] = *(const half8*)(abase + mt * (16 * 272) + ((kc ^ (mt & 1)) * 64));
            #pragma unroll
            for (int mt = 0; mt < 4; ++mt)
                #pragma unroll
                for (int nt = 0; nt < 2; ++nt)
                    acc[mt][nt] = __builtin_amdgcn_mfma_f32_16x16x32_f16(af[mt], bf[nt][kc], acc[mt][nt], 0, 0, 0);
        }

        // ---- packed top-2: ~6 VALU/score, index rides in the low 9 bits
        #pragma unroll
        for (int nt = 0; nt < 2; ++nt) {
            unsigned code = (unsigned)(tile * 64 + wn * 32 + nt * 16 + l15);
            float es = nt ? es1 : es0;
            #pragma unroll
            for (int mt = 0; mt < 4; ++mt)
                #pragma unroll
                for (int r = 0; r < 4; ++r) {
                    int s = mt * 4 + r;
                    float sc = fmaf(-2.0f, acc[mt][nt][r], es);
                    float p = __uint_as_float((__float_as_uint(sc) & 0xFFFFFE00u) | code);
                    b2[s] = fminf(b2[s], fmaxf(b1[s], p));
                    b1[s] = fminf(b1[s], p);
                }
        }
    }

    // ---- butterfly top-2 merge across the 16 lanes (l15) sharing each position
    #pragma unroll
    for (int d = 1; d < 16; d <<= 1) {
        #pragma unroll
        for (int s = 0; s < 16; ++s) {
            float ob1 = __shfl_xor(b1[s], d, 64);
            float ob2 = __shfl_xor(b2[s], d, 64);
            b2[s] = fminf(fminf(b2[s], ob2), fmaxf(b1[s], ob1));
            b1[s] = fminf(b1[s], ob1);
        }
    }
    if (l15 == 0) {
        #pragma unroll
        for (int s = 0; s < 16; ++s) {
            int m = wm * 64 + (s >> 2) * 16 + quad * 4 + (s & 3);
            mB1[wn][m] = b1[s];
            mB2[wn][m] = b2[s];
        }
    }
    __syncthreads();
    if (t < 128) {
        float a1 = mB1[0][t], c1 = mB1[1][t];
        float f1 = fminf(a1, c1);
        float f2 = fminf(fminf(mB2[0][t], mB2[1][t]), fmaxf(a1, c1));
        ish[t] = (int)(__float_as_uint(f1) & 511u);
        if (f2 - f1 < MARGIN) {
            int p = atomicAdd(cnt, 1);
            wl[p] = n0 + t;
        }
    }
    __syncthreads();

    // ---- epilogue: 4 positions x 16 channels per thread; gather 4 winner rows
    // (L2-hot emb, dwordx4), register 4x4 transpose, dwordx4 stores along hw.
    {
        int g = t & 31, cq = t >> 5;
        int hw = hw0 + 4 * g;
        int i0 = ish[4 * g + 0], i1 = ish[4 * g + 1];
        int i2 = ish[4 * g + 2], i3 = ish[4 * g + 3];
        const float4* e0 = (const float4*)(emb + (size_t)i0 * DIM) + cq * 4;
        const float4* e1 = (const float4*)(emb + (size_t)i1 * DIM) + cq * 4;
        const float4* e2 = (const float4*)(emb + (size_t)i2 * DIM) + cq * 4;
        const float4* e3 = (const float4*)(emb + (size_t)i3 * DIM) + cq * 4;
        float* ob = out + (size_t)bb * DIM * HWX + (size_t)cq * 16 * HWX + hw;
        #pragma unroll
        for (int cc = 0; cc < 4; ++cc) {
            float4 r0 = e0[cc], r1 = e1[cc], r2 = e2[cc], r3 = e3[cc];
            *(float4*)(ob + (size_t)(4 * cc + 0) * HWX) = (float4){r0.x, r1.x, r2.x, r3.x};
            *(float4*)(ob + (size_t)(4 * cc + 1) * HWX) = (float4){r0.y, r1.y, r2.y, r3.y};
            *(float4*)(ob + (size_t)(4 * cc + 2) * HWX) = (float4){r0.z, r1.z, r2.z, r3.z};
            *(float4*)(ob + (size_t)(4 * cc + 3) * HWX) = (float4){r0.w, r1.w, r2.w, r3.w};
        }
    }
}

// ---------------- refine v5: 16 entries/block (was 64) -> 4x active blocks,
// 4x shorter per-block serial chain. Exact fp32 rescan, lex (s,k) winner. ----
__global__ __launch_bounds__(256) void refine_kernel(const float* __restrict__ z,
                                                     const float* __restrict__ emb,
                                                     const float* __restrict__ esq,
                                                     const int* __restrict__ wl,
                                                     const int* __restrict__ cnt,
                                                     float* __restrict__ out) {
    __shared__ __align__(16) float zsh[16][132];   // [entry][dim]
    __shared__ __align__(16) float esh[64][132];   // [code][dim], col 128 = esq
    __shared__ float rs[16][16];
    __shared__ int   ri[16][16];
    __shared__ int   nsh[16];
    __shared__ int   ksh[16];

    int t = threadIdx.x;
    int te = t & 15, tc = t >> 4;                  // entry / code group (16x16)
    int count = *cnt;

    for (int base = blockIdx.x * 16; base < count; base += 256 * 16) {
        {   // stage 16 z rows: 16 threads/entry, 8 strided dwords each
            int e = t >> 4, d = t & 15;
            int ge = base + e;
            if (ge > count - 1) ge = count - 1;    // clamp: duplicate entries benign
            int n = wl[ge];
            if (d == 0) nsh[e] = n;
            int b = n >> 12, hw = n & 4095;
            const float* zp = z + (size_t)b * DIM * HWX + hw;
            #pragma unroll
            for (int jj = 0; jj < 8; ++jj)
                zsh[e][d + 16 * jj] = zp[(size_t)(d + 16 * jj) * HWX];
        }

        float bs = 3.0e38f; int bk = 0;            // per-thread lex-min over its 32 codes

        for (int tile = 0; tile < 8; ++tile) {
            __syncthreads();    // zsh/nsh ready (tile 0); prev esh reads done (tile>0)
            {   // stage 64 codes x 128 dims fp32, coalesced b128; esq into col 128
                const float4* gsrc = (const float4*)(emb + (size_t)tile * 64 * DIM);
                #pragma unroll
                for (int jj = 0; jj < 8; ++jj) {
                    int f = jj * 256 + t;
                    int k = f >> 5, q = f & 31;
                    float4 v = gsrc[f];
                    *(float4*)&esh[k][q * 4] = v;
                }
                if (t < 64) esh[t][128] = esq[tile * 64 + t];
            }
            __syncthreads();

            float acc[4] = {0.f, 0.f, 0.f, 0.f};   // 1 entry x 4 codes
            #pragma unroll 4
            for (int c4 = 0; c4 < 32; ++c4) {
                float4 zv = *(const float4*)&zsh[te][c4 * 4];
                #pragma unroll
                for (int j = 0; j < 4; ++j) {
                    float4 ev = *(const float4*)&esh[tc * 4 + j][c4 * 4];
                    acc[j] = fmaf(zv.x, ev.x, acc[j]);
                    acc[j] = fmaf(zv.y, ev.y, acc[j]);
                    acc[j] = fmaf(zv.z, ev.z, acc[j]);
                    acc[j] = fmaf(zv.w, ev.w, acc[j]);
                }
            }
            #pragma unroll
            for (int j = 0; j < 4; ++j) {          // k ascending per thread
                int k = tile * 64 + tc * 4 + j;
                float es = esh[tc * 4 + j][128];
                float s = fmaf(-2.f, acc[j], es);
                if (s < bs) { bs = s; bk = k; }
            }
        }
        __syncthreads();   // all esh/zsh reads done
        rs[te][tc] = bs; ri[te][tc] = bk;
        __syncthreads();
        if (t < 16) {
            float s = rs[t][0]; int k = ri[t][0];
            #pragma unroll
            for (int q = 1; q < 16; ++q) {         // lex (s,k): first-min over all 512
                float s2 = rs[t][q]; int k2 = ri[t][q];
                bool take = (s2 < s) || (s2 == s && k2 < k);
                s = take ? s2 : s;
                k = take ? k2 : k;
            }
            ksh[t] = k;
        }
        __syncthreads();
        {   // write corrected rows: 16 threads/entry x 8 dims each
            int e = t >> 4, d = t & 15;
            int n = nsh[e];
            int b = n >> 12, hw = n & 4095;
            int kk = ksh[e];
            const float* er = emb + (size_t)kk * DIM;
            float* ob = out + (size_t)b * DIM * HWX + hw;
            #pragma unroll
            for (int jj = 0; jj < 8; ++jj)
                ob[(size_t)(d + 16 * jj) * HWX] = er[d + 16 * jj];
        }
        __syncthreads();   // protect zsh/nsh/ksh for next grid-stride round
    }
}

// ---------------- legacy fallback (round-1, verified) ----------------
__global__ void esq_kernel(const float* __restrict__ emb, float* __restrict__ e_sq) {
    int k = blockIdx.x * blockDim.x + threadIdx.x;
    if (k < NUM_EMB) {
        const float4* row = (const float4*)(emb + k * DIM);
        float s0 = 0.f, s1 = 0.f, s2 = 0.f, s3 = 0.f;
        #pragma unroll
        for (int c = 0; c < DIM / 4; ++c) {
            float4 v = row[c];
            s0 = fmaf(v.x, v.x, s0); s1 = fmaf(v.y, v.y, s1);
            s2 = fmaf(v.z, v.z, s2); s3 = fmaf(v.w, v.w, s3);
        }
        e_sq[k] = (s0 + s1) + (s2 + s3);
    }
}

__global__ __launch_bounds__(256) void vq_kernel(const float* __restrict__ z,
                                                 const float* __restrict__ emb,
                                                 const float* __restrict__ e_sq,
                                                 float* __restrict__ out) {
    int n = blockIdx.x * 256 + threadIdx.x;
    int b = n >> 12, hw = n & 4095;
    const float* zb = z + (size_t)b * DIM * HWX + hw;
    float zr[DIM];
    #pragma unroll
    for (int c = 0; c < DIM; ++c) zr[c] = zb[(size_t)c * HWX];
    float best = FLT_MAX; int besti = 0;
    for (int k = 0; k < NUM_EMB; ++k) {
        const float4* er = (const float4*)(emb + k * DIM);
        float d0 = 0.f, d1 = 0.f, d2 = 0.f, d3 = 0.f;
        #pragma unroll
        for (int c = 0; c < DIM / 4; ++c) {
            float4 e = er[c];
            d0 = fmaf(zr[4 * c + 0], e.x, d0);
            d1 = fmaf(zr[4 * c + 1], e.y, d1);
            d2 = fmaf(zr[4 * c + 2], e.z, d2);
            d3 = fmaf(zr[4 * c + 3], e.w, d3);
        }
        float s = e_sq[k] - 2.f * ((d0 + d1) + (d2 + d3));
        if (s < best) { best = s; besti = k; }
    }
    float* ob = out + (size_t)b * DIM * HWX + hw;
    const float4* sel = (const float4*)(emb + (size_t)besti * DIM);
    #pragma unroll
    for (int c4 = 0; c4 < DIM / 4; ++c4) {
        float4 v = sel[c4];
        ob[(size_t)(4 * c4 + 0) * HWX] = v.x;
        ob[(size_t)(4 * c4 + 1) * HWX] = v.y;
        ob[(size_t)(4 * c4 + 2) * HWX] = v.z;
        ob[(size_t)(4 * c4 + 3) * HWX] = v.w;
    }
}

extern "C" void kernel_launch(void* const* d_in, const int* in_sizes, int n_in,
                              void* d_out, int out_size, void* d_ws, size_t ws_size,
                              hipStream_t stream) {
    const float* z   = (const float*)d_in[0];   // (32,128,64,64) fp32
    const float* emb = (const float*)d_in[1];   // (512,128) fp32
    float* out = (float*)d_out;

    if (ws_size < WS_NEED) {
        // fallback: verified round-1 path
        float* e_sq = (float*)d_ws;
        esq_kernel<<<(NUM_EMB + 255) / 256, 256, 0, stream>>>(emb, e_sq);
        vq_kernel<<<NPOS / 256, 256, 0, stream>>>(z, emb, e_sq, out);
        return;
    }

    char* ws = (char*)d_ws;
    _Float16* e16 = (_Float16*)(ws + WS_E16);
    float*    esq = (float*)(ws + WS_ESQ);
    int*      wl   = (int*)(ws + WS_WL);
    int*      cnt  = (int*)(ws + WS_CNT);

    prep_kernel<<<2, 256, 0, stream>>>(emb, e16, esq, cnt);
    gemm_argmin<<<NPOS / 128, 256, 0, stream>>>(z, e16, esq, emb, out, wl, cnt);
    refine_kernel<<<256, 256, 0, stream>>>(z, emb, esq, wl, cnt, out);
}